// Round 1
// baseline (524.219 us; speedup 1.0000x reference)
//
#include <hip/hip_runtime.h>

#define BB 32
#define AA 8
#define NN 20000
#define DD 128
#define PP 50
#define DELTA 1e-3f

// ---------------- conv1: [32,4,84,84] * [32,4,8,8] s4 -> [32,32,20,20] relu ----------------
__global__ __launch_bounds__(256) void conv1_k(const float* __restrict__ x,
                                               const float* __restrict__ w,
                                               const float* __restrict__ bias,
                                               float* __restrict__ y) {
    int idx = blockIdx.x * 256 + threadIdx.x;
    if (idx >= 32 * 32 * 20 * 20) return;
    int ox = idx % 20;
    int t = idx / 20;
    int oy = t % 20; t /= 20;
    int oc = t % 32;
    int b = t / 32;
    float acc = bias[oc];
    const float* xb = x + (size_t)b * 4 * 84 * 84;
    const float* wk = w + oc * 4 * 64;
    for (int ic = 0; ic < 4; ic++) {
        const float* xc = xb + ic * 84 * 84 + (oy * 4) * 84 + ox * 4;
        const float* wc = wk + ic * 64;
#pragma unroll
        for (int ky = 0; ky < 8; ky++)
#pragma unroll
            for (int kx = 0; kx < 8; kx++)
                acc += xc[ky * 84 + kx] * wc[ky * 8 + kx];
    }
    y[idx] = fmaxf(acc, 0.f);
}

// ---------------- conv2: [32,32,20,20] * [64,32,4,4] s2 -> [32,64,9,9] relu ----------------
__global__ __launch_bounds__(256) void conv2_k(const float* __restrict__ x,
                                               const float* __restrict__ w,
                                               const float* __restrict__ bias,
                                               float* __restrict__ y) {
    int idx = blockIdx.x * 256 + threadIdx.x;
    if (idx >= 32 * 64 * 9 * 9) return;
    int ox = idx % 9;
    int t = idx / 9;
    int oy = t % 9; t /= 9;
    int oc = t % 64;
    int b = t / 64;
    float acc = bias[oc];
    const float* xb = x + (size_t)b * 32 * 400;
    const float* wk = w + oc * 32 * 16;
    for (int ic = 0; ic < 32; ic++) {
        const float* xc = xb + ic * 400 + (oy * 2) * 20 + ox * 2;
        const float* wc = wk + ic * 16;
#pragma unroll
        for (int ky = 0; ky < 4; ky++)
#pragma unroll
            for (int kx = 0; kx < 4; kx++)
                acc += xc[ky * 20 + kx] * wc[ky * 4 + kx];
    }
    y[idx] = fmaxf(acc, 0.f);
}

// ---------------- conv3: [32,64,9,9] * [64,64,3,3] s1 -> [32,64,7,7] relu ----------------
__global__ __launch_bounds__(256) void conv3_k(const float* __restrict__ x,
                                               const float* __restrict__ w,
                                               const float* __restrict__ bias,
                                               float* __restrict__ y) {
    int idx = blockIdx.x * 256 + threadIdx.x;
    if (idx >= 32 * 64 * 7 * 7) return;
    int ox = idx % 7;
    int t = idx / 7;
    int oy = t % 7; t /= 7;
    int oc = t % 64;
    int b = t / 64;
    float acc = bias[oc];
    const float* xb = x + (size_t)b * 64 * 81;
    const float* wk = w + oc * 64 * 9;
    for (int ic = 0; ic < 64; ic++) {
        const float* xc = xb + ic * 81 + oy * 9 + ox;
        const float* wc = wk + ic * 9;
#pragma unroll
        for (int ky = 0; ky < 3; ky++)
#pragma unroll
            for (int kx = 0; kx < 3; kx++)
                acc += xc[ky * 9 + kx] * wc[ky * 3 + kx];
    }
    y[idx] = fmaxf(acc, 0.f);
}

// ---------------- fc: [32,3136] @ [128,3136]^T + b -> h [32,128] ----------------
__global__ __launch_bounds__(128) void fc_k(const float* __restrict__ x,
                                            const float* __restrict__ w,
                                            const float* __restrict__ bias,
                                            float* __restrict__ h) {
    __shared__ float sx[3136];
    int b = blockIdx.x, tid = threadIdx.x;  // 128 threads
    for (int i = tid; i < 3136; i += 128) sx[i] = x[(size_t)b * 3136 + i];
    __syncthreads();
    const float4* wr = (const float4*)(w + (size_t)tid * 3136);
    const float4* sx4 = (const float4*)sx;
    float acc = 0.f;
    for (int i = 0; i < 784; i++) {
        float4 a = sx4[i], c = wr[i];
        acc += a.x * c.x + a.y * c.y + a.z * c.z + a.w * c.w;
    }
    h[b * 128 + tid] = acc + bias[tid];
}

// ---------------- dist: d2[b][n] = sum_d (h[b][d] - keys[act[b]][n][d])^2 ----------------
// grid (40, 32), block 256. Half-wave (32 lanes) per key row; lane holds float4 slice of h.
__global__ __launch_bounds__(256) void dist_k(const float* __restrict__ h,
                                              const int* __restrict__ actions,
                                              const float* __restrict__ keys,
                                              float* __restrict__ d2) {
    int b = blockIdx.y;
    int a = actions[b];
    int lane = threadIdx.x & 63;
    int wave = threadIdx.x >> 6;
    int half = lane >> 5;
    int l32 = lane & 31;
    float4 hv = ((const float4*)(h + b * DD))[l32];
    const float* kb = keys + (size_t)a * NN * DD;
    int rowend = blockIdx.x * 512 + 512;
    for (int r = blockIdx.x * 512 + wave * 2 + half; r < rowend; r += 8) {
        if (r < NN) {
            float4 kv = ((const float4*)(kb + (size_t)r * DD))[l32];
            float dx = hv.x - kv.x, dy = hv.y - kv.y, dz = hv.z - kv.z, dw = hv.w - kv.w;
            float s = dx * dx + dy * dy + dz * dz + dw * dw;
#pragma unroll
            for (int m = 16; m >= 1; m >>= 1) s += __shfl_xor(s, m);
            if (l32 == 0) d2[(size_t)b * NN + r] = s;
        }
    }
}

// ---------------- topk: exact 50x min-extraction per sample, then weighted sum ----------------
__global__ __launch_bounds__(256) void topk_k(float* d2,  // not restrict: re-read after marking
                                              const float* __restrict__ values,
                                              const int* __restrict__ actions,
                                              float* __restrict__ q) {
    int b = blockIdx.x, tid = threadIdx.x;
    __shared__ float sm_d[PP];
    __shared__ int sm_i[PP];
    __shared__ float wmin[4];
    __shared__ int wmini[4];
    float* db = d2 + (size_t)b * NN;
    const float4* d4 = (const float4*)db;
    for (int p = 0; p < PP; p++) {
        float best = INFINITY;
        int bi = 0x7fffffff;
        for (int i = tid; i < NN / 4; i += 256) {
            float4 v = d4[i];
            if (v.x < best) { best = v.x; bi = 4 * i; }
            if (v.y < best) { best = v.y; bi = 4 * i + 1; }
            if (v.z < best) { best = v.z; bi = 4 * i + 2; }
            if (v.w < best) { best = v.w; bi = 4 * i + 3; }
        }
        // wave(64) argmin reduce, tie-break lower index (lax.top_k is stable)
#pragma unroll
        for (int m = 32; m >= 1; m >>= 1) {
            float ob = __shfl_xor(best, m);
            int oi = __shfl_xor(bi, m);
            if (ob < best || (ob == best && oi < bi)) { best = ob; bi = oi; }
        }
        int wv = tid >> 6;
        if ((tid & 63) == 0) { wmin[wv] = best; wmini[wv] = bi; }
        __syncthreads();
        if (tid == 0) {
            float bb = wmin[0]; int bbi = wmini[0];
#pragma unroll
            for (int k = 1; k < 4; k++)
                if (wmin[k] < bb || (wmin[k] == bb && wmini[k] < bbi)) { bb = wmin[k]; bbi = wmini[k]; }
            sm_d[p] = bb; sm_i[p] = bbi;
            db[bbi] = INFINITY;  // mark taken
        }
        __syncthreads();
    }
    // weights + value gather (parallel over 64 lanes)
    __shared__ float sw[64], swv[64];
    if (tid < 64) {
        float w = 0.f, wvv = 0.f;
        if (tid < PP) {
            float dd = fmaxf(sm_d[tid], 0.f);
            w = 1.f / (dd + DELTA);
            int a = actions[b];
            wvv = w * values[(size_t)a * NN + sm_i[tid]];
        }
        sw[tid] = w; swv[tid] = wvv;
    }
    __syncthreads();
    if (tid == 0) {
        float W = 0.f, WV = 0.f;
        for (int k = 0; k < PP; k++) { W += sw[k]; WV += swv[k]; }
        q[b] = WV / W;
    }
}

extern "C" void kernel_launch(void* const* d_in, const int* in_sizes, int n_in,
                              void* d_out, int out_size, void* d_ws, size_t ws_size,
                              hipStream_t stream) {
    const float* states = (const float*)d_in[0];
    const int* actions = (const int*)d_in[1];
    const float* c1w = (const float*)d_in[2];
    const float* c1b = (const float*)d_in[3];
    const float* c2w = (const float*)d_in[4];
    const float* c2b = (const float*)d_in[5];
    const float* c3w = (const float*)d_in[6];
    const float* c3b = (const float*)d_in[7];
    const float* fcw = (const float*)d_in[8];
    const float* fcb = (const float*)d_in[9];
    const float* keys = (const float*)d_in[10];
    const float* vals = (const float*)d_in[11];
    float* out = (float*)d_out;

    float* ws = (float*)d_ws;
    float* c1o = ws;                   // 32*32*20*20 = 409600
    float* c2o = c1o + 409600;         // 32*64*9*9   = 165888
    float* c3o = c2o + 165888;         // 32*64*7*7   = 100352
    float* h   = c3o + 100352;         // 32*128      = 4096
    float* d2  = h + 4096;             // 32*20000    = 640000

    conv1_k<<<(409600 + 255) / 256, 256, 0, stream>>>(states, c1w, c1b, c1o);
    conv2_k<<<(165888 + 255) / 256, 256, 0, stream>>>(c1o, c2w, c2b, c2o);
    conv3_k<<<(100352 + 255) / 256, 256, 0, stream>>>(c2o, c3w, c3b, c3o);
    fc_k<<<32, 128, 0, stream>>>(c3o, fcw, fcb, h);
    dist_k<<<dim3(40, 32), 256, 0, stream>>>(h, actions, keys, d2);
    topk_k<<<32, 256, 0, stream>>>(d2, vals, actions, out);
}

// Round 2
// 427.460 us; speedup vs baseline: 1.2264x; 1.2264x over previous
//
#include <hip/hip_runtime.h>

#define BB 32
#define AA 8
#define NN 20000
#define DD 128
#define PP 50
#define DELTA 1e-3f
#define CH 16
#define CHUNK 1250  // NN / CH

// ---------------- conv1: [32,4,84,84] * [32,4,8,8] s4 -> [32,32,20,20] relu ----------------
__global__ __launch_bounds__(256) void conv1_k(const float* __restrict__ x,
                                               const float* __restrict__ w,
                                               const float* __restrict__ bias,
                                               float* __restrict__ y) {
    int idx = blockIdx.x * 256 + threadIdx.x;
    if (idx >= 32 * 32 * 20 * 20) return;
    int ox = idx % 20;
    int t = idx / 20;
    int oy = t % 20; t /= 20;
    int oc = t % 32;
    int b = t / 32;
    float acc = bias[oc];
    const float* xb = x + (size_t)b * 4 * 84 * 84;
    const float* wk = w + oc * 4 * 64;
    for (int ic = 0; ic < 4; ic++) {
        const float* xc = xb + ic * 84 * 84 + (oy * 4) * 84 + ox * 4;
        const float* wc = wk + ic * 64;
#pragma unroll
        for (int ky = 0; ky < 8; ky++)
#pragma unroll
            for (int kx = 0; kx < 8; kx++)
                acc += xc[ky * 84 + kx] * wc[ky * 8 + kx];
    }
    y[idx] = fmaxf(acc, 0.f);
}

// ---------------- conv2: [32,32,20,20] * [64,32,4,4] s2 -> [32,64,9,9] relu ----------------
__global__ __launch_bounds__(256) void conv2_k(const float* __restrict__ x,
                                               const float* __restrict__ w,
                                               const float* __restrict__ bias,
                                               float* __restrict__ y) {
    int idx = blockIdx.x * 256 + threadIdx.x;
    if (idx >= 32 * 64 * 9 * 9) return;
    int ox = idx % 9;
    int t = idx / 9;
    int oy = t % 9; t /= 9;
    int oc = t % 64;
    int b = t / 64;
    float acc = bias[oc];
    const float* xb = x + (size_t)b * 32 * 400;
    const float* wk = w + oc * 32 * 16;
    for (int ic = 0; ic < 32; ic++) {
        const float* xc = xb + ic * 400 + (oy * 2) * 20 + ox * 2;
        const float* wc = wk + ic * 16;
#pragma unroll
        for (int ky = 0; ky < 4; ky++)
#pragma unroll
            for (int kx = 0; kx < 4; kx++)
                acc += xc[ky * 20 + kx] * wc[ky * 4 + kx];
    }
    y[idx] = fmaxf(acc, 0.f);
}

// ---------------- conv3: [32,64,9,9] * [64,64,3,3] s1 -> [32,64,7,7] relu ----------------
__global__ __launch_bounds__(256) void conv3_k(const float* __restrict__ x,
                                               const float* __restrict__ w,
                                               const float* __restrict__ bias,
                                               float* __restrict__ y) {
    int idx = blockIdx.x * 256 + threadIdx.x;
    if (idx >= 32 * 64 * 7 * 7) return;
    int ox = idx % 7;
    int t = idx / 7;
    int oy = t % 7; t /= 7;
    int oc = t % 64;
    int b = t / 64;
    float acc = bias[oc];
    const float* xb = x + (size_t)b * 64 * 81;
    const float* wk = w + oc * 64 * 9;
    for (int ic = 0; ic < 64; ic++) {
        const float* xc = xb + ic * 81 + oy * 9 + ox;
        const float* wc = wk + ic * 9;
#pragma unroll
        for (int ky = 0; ky < 3; ky++)
#pragma unroll
            for (int kx = 0; kx < 3; kx++)
                acc += xc[ky * 9 + kx] * wc[ky * 3 + kx];
    }
    y[idx] = fmaxf(acc, 0.f);
}

// ---------------- fc: [32,3136] @ [128,3136]^T + b -> h [32,128] ----------------
// grid 256 = (b, oc-group of 16); block 256 = 16 outputs x 16 k-slices.
__global__ __launch_bounds__(256) void fc_k(const float* __restrict__ x,
                                            const float* __restrict__ w,
                                            const float* __restrict__ bias,
                                            float* __restrict__ h) {
    __shared__ float sx[3136];
    int b = blockIdx.x >> 3;
    int g = blockIdx.x & 7;
    int tid = threadIdx.x;
    const float4* xr = (const float4*)(x + (size_t)b * 3136);
    float4* sx4w = (float4*)sx;
    for (int i = tid; i < 784; i += 256) sx4w[i] = xr[i];
    __syncthreads();
    int oc_local = tid >> 4;      // 0..15
    int kslice = tid & 15;        // 0..15
    int oc = g * 16 + oc_local;
    const float4* wr = (const float4*)(w + (size_t)oc * 3136);
    const float4* sx4 = (const float4*)sx;
    float acc = 0.f;
#pragma unroll 7
    for (int j = 0; j < 49; j++) {
        int i = kslice + 16 * j;
        float4 a = sx4[i], c = wr[i];
        acc += a.x * c.x + a.y * c.y + a.z * c.z + a.w * c.w;
    }
    // reduce over the 16 k-slice lanes (consecutive lanes within the wave)
#pragma unroll
    for (int m = 8; m >= 1; m >>= 1) acc += __shfl_xor(acc, m);
    if (kslice == 0) h[b * 128 + oc] = acc + bias[oc];
}

// ---------------- stage 1: fused distance + local top-50 per 1250-row chunk ----------------
// grid (CH, B), block 256 (4 waves, 8 half-wave row slots).
__global__ __launch_bounds__(256) void distsel_k(const float* __restrict__ h,
                                                 const int* __restrict__ actions,
                                                 const float* __restrict__ keys,
                                                 float* __restrict__ cand_d,
                                                 int* __restrict__ cand_i) {
    int b = blockIdx.y;
    int chunk = blockIdx.x;
    int r0 = chunk * CHUNK;
    int a = actions[b];
    int tid = threadIdx.x;
    int lane = tid & 63;
    int wave = tid >> 6;
    int half = lane >> 5;
    int l32 = lane & 31;
    __shared__ float sd[CHUNK];
    __shared__ float wd[4];
    __shared__ int wi[4];
    float4 hv = ((const float4*)(h + b * DD))[l32];
    const float* kb = keys + (size_t)a * NN * DD + (size_t)r0 * DD;
    for (int r = wave * 2 + half; r < CHUNK; r += 8) {
        float4 kv = ((const float4*)(kb + (size_t)r * DD))[l32];
        float dx = hv.x - kv.x, dy = hv.y - kv.y, dz = hv.z - kv.z, dw = hv.w - kv.w;
        float s = dx * dx + dy * dy + dz * dz + dw * dw;
#pragma unroll
        for (int m = 16; m >= 1; m >>= 1) s += __shfl_xor(s, m);
        if (l32 == 0) sd[r] = s;
    }
    __syncthreads();
    float* cd = cand_d + ((size_t)b * CH + chunk) * PP;
    int* ci = cand_i + ((size_t)b * CH + chunk) * PP;
    for (int p = 0; p < PP; p++) {
        float best = INFINITY;
        int bi = 0x7fffffff;
        for (int i = tid; i < CHUNK; i += 256) {
            float v = sd[i];
            if (v < best) { best = v; bi = i; }   // ascending scan keeps lowest idx on ties
        }
#pragma unroll
        for (int m = 32; m >= 1; m >>= 1) {
            float ob = __shfl_xor(best, m);
            int oi = __shfl_xor(bi, m);
            if (ob < best || (ob == best && oi < bi)) { best = ob; bi = oi; }
        }
        if (lane == 0) { wd[wave] = best; wi[wave] = bi; }
        __syncthreads();
        if (tid == 0) {
            float bb = wd[0]; int bbi = wi[0];
#pragma unroll
            for (int k = 1; k < 4; k++)
                if (wd[k] < bb || (wd[k] == bb && wi[k] < bbi)) { bb = wd[k]; bbi = wi[k]; }
            cd[p] = bb; ci[p] = r0 + bbi;
            sd[bbi] = INFINITY;
        }
        __syncthreads();
    }
}

// ---------------- stage 2: merge 16x50 candidates, exact top-50, weighted sum ----------------
__global__ __launch_bounds__(256) void merge_k(const float* __restrict__ cand_d,
                                               const int* __restrict__ cand_i,
                                               const float* __restrict__ values,
                                               const int* __restrict__ actions,
                                               float* __restrict__ q) {
    const int M = CH * PP;  // 800
    int b = blockIdx.x, tid = threadIdx.x;
    int lane = tid & 63, wave = tid >> 6;
    __shared__ float md[M];
    __shared__ int mi[M];
    __shared__ float wd[4], wgi_d;
    __shared__ int wgi[4], wpos[4];
    __shared__ float seld[PP];
    __shared__ int seli[PP];
    (void)wgi_d;
    for (int i = tid; i < M; i += 256) {
        md[i] = cand_d[(size_t)b * M + i];
        mi[i] = cand_i[(size_t)b * M + i];
    }
    __syncthreads();
    for (int p = 0; p < PP; p++) {
        float best = INFINITY;
        int bgi = 0x7fffffff, bpos = 0;
        for (int i = tid; i < M; i += 256) {
            float v = md[i];
            int gi = mi[i];
            if (v < best || (v == best && gi < bgi)) { best = v; bgi = gi; bpos = i; }
        }
#pragma unroll
        for (int m = 32; m >= 1; m >>= 1) {
            float ob = __shfl_xor(best, m);
            int ogi = __shfl_xor(bgi, m);
            int opos = __shfl_xor(bpos, m);
            if (ob < best || (ob == best && ogi < bgi)) { best = ob; bgi = ogi; bpos = opos; }
        }
        if (lane == 0) { wd[wave] = best; wgi[wave] = bgi; wpos[wave] = bpos; }
        __syncthreads();
        if (tid == 0) {
            float bb = wd[0]; int bbgi = wgi[0], bbpos = wpos[0];
#pragma unroll
            for (int k = 1; k < 4; k++)
                if (wd[k] < bb || (wd[k] == bb && wgi[k] < bbgi)) { bb = wd[k]; bbgi = wgi[k]; bbpos = wpos[k]; }
            seld[p] = bb; seli[p] = bbgi;
            md[bbpos] = INFINITY;
        }
        __syncthreads();
    }
    if (tid < 64) {
        int a = actions[b];
        float w = 0.f, wv = 0.f;
        if (tid < PP) {
            float dd = fmaxf(seld[tid], 0.f);
            w = 1.f / (dd + DELTA);
            wv = w * values[(size_t)a * NN + seli[tid]];
        }
#pragma unroll
        for (int m = 32; m >= 1; m >>= 1) {
            w += __shfl_xor(w, m);
            wv += __shfl_xor(wv, m);
        }
        if (tid == 0) q[b] = wv / w;
    }
}

extern "C" void kernel_launch(void* const* d_in, const int* in_sizes, int n_in,
                              void* d_out, int out_size, void* d_ws, size_t ws_size,
                              hipStream_t stream) {
    const float* states = (const float*)d_in[0];
    const int* actions = (const int*)d_in[1];
    const float* c1w = (const float*)d_in[2];
    const float* c1b = (const float*)d_in[3];
    const float* c2w = (const float*)d_in[4];
    const float* c2b = (const float*)d_in[5];
    const float* c3w = (const float*)d_in[6];
    const float* c3b = (const float*)d_in[7];
    const float* fcw = (const float*)d_in[8];
    const float* fcb = (const float*)d_in[9];
    const float* keys = (const float*)d_in[10];
    const float* vals = (const float*)d_in[11];
    float* out = (float*)d_out;

    float* ws = (float*)d_ws;
    float* c1o = ws;                    // 409600
    float* c2o = c1o + 409600;          // 165888
    float* c3o = c2o + 165888;          // 100352
    float* h   = c3o + 100352;          // 4096
    float* cand_d = h + 4096;           // 32*16*50 = 25600
    int* cand_i = (int*)(cand_d + 25600);  // 25600

    conv1_k<<<(409600 + 255) / 256, 256, 0, stream>>>(states, c1w, c1b, c1o);
    conv2_k<<<(165888 + 255) / 256, 256, 0, stream>>>(c1o, c2w, c2b, c2o);
    conv3_k<<<(100352 + 255) / 256, 256, 0, stream>>>(c2o, c3w, c3b, c3o);
    fc_k<<<256, 256, 0, stream>>>(c3o, fcw, fcb, h);
    distsel_k<<<dim3(CH, BB), 256, 0, stream>>>(h, actions, keys, cand_d, cand_i);
    merge_k<<<BB, 256, 0, stream>>>(cand_d, cand_i, vals, actions, out);
}

// Round 3
// 365.647 us; speedup vs baseline: 1.4337x; 1.1691x over previous
//
#include <hip/hip_runtime.h>

#define BB 32
#define AA 8
#define NN 20000
#define DD 128
#define PP 50
#define DELTA 1e-3f
#define CH 16
#define CHUNK 1250  // NN / CH

// ---------------- conv1: [32,4,84,84] * [32,4,8,8] s4 -> [32,32,20,20] relu ----------------
__global__ __launch_bounds__(256) void conv1_k(const float* __restrict__ x,
                                               const float* __restrict__ w,
                                               const float* __restrict__ bias,
                                               float* __restrict__ y) {
    int idx = blockIdx.x * 256 + threadIdx.x;
    if (idx >= 32 * 32 * 20 * 20) return;
    int ox = idx % 20;
    int t = idx / 20;
    int oy = t % 20; t /= 20;
    int oc = t % 32;
    int b = t / 32;
    float acc = bias[oc];
    const float* xb = x + (size_t)b * 4 * 84 * 84;
    const float* wk = w + oc * 4 * 64;
    for (int ic = 0; ic < 4; ic++) {
        const float* xc = xb + ic * 84 * 84 + (oy * 4) * 84 + ox * 4;  // 16B-aligned
        const float* wc = wk + ic * 64;
#pragma unroll
        for (int ky = 0; ky < 8; ky++) {
            const float4* xr = (const float4*)(xc + ky * 84);
            const float4* wr = (const float4*)(wc + ky * 8);
            float4 x0 = xr[0], x1 = xr[1];
            float4 w0 = wr[0], w1 = wr[1];
            acc += x0.x * w0.x + x0.y * w0.y + x0.z * w0.z + x0.w * w0.w
                 + x1.x * w1.x + x1.y * w1.y + x1.z * w1.z + x1.w * w1.w;
        }
    }
    y[idx] = fmaxf(acc, 0.f);
}

// ---------------- conv2: [32,32,20,20] * [64,32,4,4] s2 -> [32,64,9,9] relu ----------------
__global__ __launch_bounds__(256) void conv2_k(const float* __restrict__ x,
                                               const float* __restrict__ w,
                                               const float* __restrict__ bias,
                                               float* __restrict__ y) {
    int idx = blockIdx.x * 256 + threadIdx.x;
    if (idx >= 32 * 64 * 9 * 9) return;
    int ox = idx % 9;
    int t = idx / 9;
    int oy = t % 9; t /= 9;
    int oc = t % 64;
    int b = t / 64;
    float acc = bias[oc];
    const float* xb = x + (size_t)b * 32 * 400;
    const float* wk = w + oc * 32 * 16;
    for (int ic = 0; ic < 32; ic++) {
        const float* xc = xb + ic * 400 + (oy * 2) * 20 + ox * 2;  // 8B-aligned
        const float* wc = wk + ic * 16;                            // 16B-aligned
#pragma unroll
        for (int ky = 0; ky < 4; ky++) {
            const float2* xr = (const float2*)(xc + ky * 20);
            float2 x0 = xr[0], x1 = xr[1];
            float4 wv = ((const float4*)(wc + ky * 4))[0];
            acc += x0.x * wv.x + x0.y * wv.y + x1.x * wv.z + x1.y * wv.w;
        }
    }
    y[idx] = fmaxf(acc, 0.f);
}

// ---------------- conv3: [32,64,9,9] * [64,64,3,3] s1 -> [32,64,7,7] relu ----------------
__global__ __launch_bounds__(256) void conv3_k(const float* __restrict__ x,
                                               const float* __restrict__ w,
                                               const float* __restrict__ bias,
                                               float* __restrict__ y) {
    int idx = blockIdx.x * 256 + threadIdx.x;
    if (idx >= 32 * 64 * 7 * 7) return;
    int ox = idx % 7;
    int t = idx / 7;
    int oy = t % 7; t /= 7;
    int oc = t % 64;
    int b = t / 64;
    float acc = bias[oc];
    const float* xb = x + (size_t)b * 64 * 81;
    const float* wk = w + oc * 64 * 9;
    for (int ic = 0; ic < 64; ic++) {
        const float* xc = xb + ic * 81 + oy * 9 + ox;
        const float* wc = wk + ic * 9;
#pragma unroll
        for (int ky = 0; ky < 3; ky++)
#pragma unroll
            for (int kx = 0; kx < 3; kx++)
                acc += xc[ky * 9 + kx] * wc[ky * 3 + kx];
    }
    y[idx] = fmaxf(acc, 0.f);
}

// ---------------- fc: [32,3136] @ [128,3136]^T + b -> h [32,128] ----------------
__global__ __launch_bounds__(256) void fc_k(const float* __restrict__ x,
                                            const float* __restrict__ w,
                                            const float* __restrict__ bias,
                                            float* __restrict__ h) {
    __shared__ float sx[3136];
    int b = blockIdx.x >> 3;
    int g = blockIdx.x & 7;
    int tid = threadIdx.x;
    const float4* xr = (const float4*)(x + (size_t)b * 3136);
    float4* sx4w = (float4*)sx;
    for (int i = tid; i < 784; i += 256) sx4w[i] = xr[i];
    __syncthreads();
    int oc_local = tid >> 4;
    int kslice = tid & 15;
    int oc = g * 16 + oc_local;
    const float4* wr = (const float4*)(w + (size_t)oc * 3136);
    const float4* sx4 = (const float4*)sx;
    float acc = 0.f;
#pragma unroll 7
    for (int j = 0; j < 49; j++) {
        int i = kslice + 16 * j;
        float4 a = sx4[i], c = wr[i];
        acc += a.x * c.x + a.y * c.y + a.z * c.z + a.w * c.w;
    }
#pragma unroll
    for (int m = 8; m >= 1; m >>= 1) acc += __shfl_xor(acc, m);
    if (kslice == 0) h[b * 128 + oc] = acc + bias[oc];
}

// ---------------- dist2: d2[b][n] = ||h[b] - keys[act[b]][n]||^2 ----------------
// grid (500, 32), block 256. Each half-wave computes 5 rows, all loads issued up-front.
__global__ __launch_bounds__(256) void dist2_k(const float* __restrict__ h,
                                               const int* __restrict__ actions,
                                               const float* __restrict__ keys,
                                               float* __restrict__ d2) {
    int b = blockIdx.y;
    int a = actions[b];
    int tid = threadIdx.x;
    int hw = tid >> 5;       // half-wave 0..7
    int l32 = tid & 31;
    float4 hv = ((const float4*)(h + b * DD))[l32];
    const float* kb = keys + (size_t)a * NN * DD;
    int r0 = blockIdx.x * 40 + hw * 5;
    float s0, s1, s2, s3, s4;
    {
        float4 k0 = ((const float4*)(kb + (size_t)(r0 + 0) * DD))[l32];
        float4 k1 = ((const float4*)(kb + (size_t)(r0 + 1) * DD))[l32];
        float4 k2 = ((const float4*)(kb + (size_t)(r0 + 2) * DD))[l32];
        float4 k3 = ((const float4*)(kb + (size_t)(r0 + 3) * DD))[l32];
        float4 k4 = ((const float4*)(kb + (size_t)(r0 + 4) * DD))[l32];
        float dx, dy, dz, dw;
        dx = hv.x - k0.x; dy = hv.y - k0.y; dz = hv.z - k0.z; dw = hv.w - k0.w;
        s0 = dx * dx + dy * dy + dz * dz + dw * dw;
        dx = hv.x - k1.x; dy = hv.y - k1.y; dz = hv.z - k1.z; dw = hv.w - k1.w;
        s1 = dx * dx + dy * dy + dz * dz + dw * dw;
        dx = hv.x - k2.x; dy = hv.y - k2.y; dz = hv.z - k2.z; dw = hv.w - k2.w;
        s2 = dx * dx + dy * dy + dz * dz + dw * dw;
        dx = hv.x - k3.x; dy = hv.y - k3.y; dz = hv.z - k3.z; dw = hv.w - k3.w;
        s3 = dx * dx + dy * dy + dz * dz + dw * dw;
        dx = hv.x - k4.x; dy = hv.y - k4.y; dz = hv.z - k4.z; dw = hv.w - k4.w;
        s4 = dx * dx + dy * dy + dz * dz + dw * dw;
    }
#pragma unroll
    for (int m = 16; m >= 1; m >>= 1) {
        s0 += __shfl_xor(s0, m);
        s1 += __shfl_xor(s1, m);
        s2 += __shfl_xor(s2, m);
        s3 += __shfl_xor(s3, m);
        s4 += __shfl_xor(s4, m);
    }
    if (l32 == 0) {
        float* dst = d2 + (size_t)b * NN + r0;
        dst[0] = s0; dst[1] = s1; dst[2] = s2; dst[3] = s3; dst[4] = s4;
    }
}

// ---------------- sel: per-chunk stable top-50 extraction from d2 ----------------
// grid (CH, B), block 256.
__global__ __launch_bounds__(256) void sel_k(const float* __restrict__ d2,
                                             float* __restrict__ cand_d,
                                             int* __restrict__ cand_i) {
    int b = blockIdx.y;
    int chunk = blockIdx.x;
    int r0 = chunk * CHUNK;
    int tid = threadIdx.x;
    int lane = tid & 63;
    int wave = tid >> 6;
    __shared__ float sd[CHUNK];
    __shared__ float wd[4];
    __shared__ int wi[4];
    const float* src = d2 + (size_t)b * NN + r0;
    for (int i = tid; i < CHUNK; i += 256) sd[i] = src[i];
    __syncthreads();
    float* cd = cand_d + ((size_t)b * CH + chunk) * PP;
    int* ci = cand_i + ((size_t)b * CH + chunk) * PP;
    for (int p = 0; p < PP; p++) {
        float best = INFINITY;
        int bi = 0x7fffffff;
        for (int i = tid; i < CHUNK; i += 256) {
            float v = sd[i];
            if (v < best) { best = v; bi = i; }  // ascending scan keeps lowest idx on ties
        }
#pragma unroll
        for (int m = 32; m >= 1; m >>= 1) {
            float ob = __shfl_xor(best, m);
            int oi = __shfl_xor(bi, m);
            if (ob < best || (ob == best && oi < bi)) { best = ob; bi = oi; }
        }
        if (lane == 0) { wd[wave] = best; wi[wave] = bi; }
        __syncthreads();
        if (tid == 0) {
            float bb = wd[0]; int bbi = wi[0];
#pragma unroll
            for (int k = 1; k < 4; k++)
                if (wd[k] < bb || (wd[k] == bb && wi[k] < bbi)) { bb = wd[k]; bbi = wi[k]; }
            cd[p] = bb; ci[p] = r0 + bbi;
            sd[bbi] = INFINITY;
        }
        __syncthreads();
    }
}

// ---------------- merge: 16x50 candidates -> exact top-50 -> weighted sum ----------------
__global__ __launch_bounds__(256) void merge_k(const float* __restrict__ cand_d,
                                               const int* __restrict__ cand_i,
                                               const float* __restrict__ values,
                                               const int* __restrict__ actions,
                                               float* __restrict__ q) {
    const int M = CH * PP;  // 800
    int b = blockIdx.x, tid = threadIdx.x;
    int lane = tid & 63, wave = tid >> 6;
    __shared__ float md[M];
    __shared__ int mi[M];
    __shared__ float wd[4];
    __shared__ int wgi[4], wpos[4];
    __shared__ float seld[PP];
    __shared__ int seli[PP];
    for (int i = tid; i < M; i += 256) {
        md[i] = cand_d[(size_t)b * M + i];
        mi[i] = cand_i[(size_t)b * M + i];
    }
    __syncthreads();
    for (int p = 0; p < PP; p++) {
        float best = INFINITY;
        int bgi = 0x7fffffff, bpos = 0;
        for (int i = tid; i < M; i += 256) {
            float v = md[i];
            int gi = mi[i];
            if (v < best || (v == best && gi < bgi)) { best = v; bgi = gi; bpos = i; }
        }
#pragma unroll
        for (int m = 32; m >= 1; m >>= 1) {
            float ob = __shfl_xor(best, m);
            int ogi = __shfl_xor(bgi, m);
            int opos = __shfl_xor(bpos, m);
            if (ob < best || (ob == best && ogi < bgi)) { best = ob; bgi = ogi; bpos = opos; }
        }
        if (lane == 0) { wd[wave] = best; wgi[wave] = bgi; wpos[wave] = bpos; }
        __syncthreads();
        if (tid == 0) {
            float bb = wd[0]; int bbgi = wgi[0], bbpos = wpos[0];
#pragma unroll
            for (int k = 1; k < 4; k++)
                if (wd[k] < bb || (wd[k] == bb && wgi[k] < bbgi)) { bb = wd[k]; bbgi = wgi[k]; bbpos = wpos[k]; }
            seld[p] = bb; seli[p] = bbgi;
            md[bbpos] = INFINITY;
        }
        __syncthreads();
    }
    if (tid < 64) {
        int a = actions[b];
        float w = 0.f, wv = 0.f;
        if (tid < PP) {
            float dd = fmaxf(seld[tid], 0.f);
            w = 1.f / (dd + DELTA);
            wv = w * values[(size_t)a * NN + seli[tid]];
        }
#pragma unroll
        for (int m = 32; m >= 1; m >>= 1) {
            w += __shfl_xor(w, m);
            wv += __shfl_xor(wv, m);
        }
        if (tid == 0) q[b] = wv / w;
    }
}

extern "C" void kernel_launch(void* const* d_in, const int* in_sizes, int n_in,
                              void* d_out, int out_size, void* d_ws, size_t ws_size,
                              hipStream_t stream) {
    const float* states = (const float*)d_in[0];
    const int* actions = (const int*)d_in[1];
    const float* c1w = (const float*)d_in[2];
    const float* c1b = (const float*)d_in[3];
    const float* c2w = (const float*)d_in[4];
    const float* c2b = (const float*)d_in[5];
    const float* c3w = (const float*)d_in[6];
    const float* c3b = (const float*)d_in[7];
    const float* fcw = (const float*)d_in[8];
    const float* fcb = (const float*)d_in[9];
    const float* keys = (const float*)d_in[10];
    const float* vals = (const float*)d_in[11];
    float* out = (float*)d_out;

    float* ws = (float*)d_ws;
    float* c1o = ws;                    // 409600 (dead after conv2 -> reused for cand_*)
    float* c2o = c1o + 409600;          // 165888
    float* c3o = c2o + 165888;          // 100352
    float* h   = c3o + 100352;          // 4096
    float* d2  = h + 4096;              // 640000
    float* cand_d = ws;                 // 25600 (overlaps dead c1o)
    int* cand_i = (int*)(cand_d + 25600);  // 25600

    conv1_k<<<(409600 + 255) / 256, 256, 0, stream>>>(states, c1w, c1b, c1o);
    conv2_k<<<(165888 + 255) / 256, 256, 0, stream>>>(c1o, c2w, c2b, c2o);
    conv3_k<<<(100352 + 255) / 256, 256, 0, stream>>>(c2o, c3w, c3b, c3o);
    fc_k<<<256, 256, 0, stream>>>(c3o, fcw, fcb, h);
    dist2_k<<<dim3(500, BB), 256, 0, stream>>>(h, actions, keys, d2);
    sel_k<<<dim3(CH, BB), 256, 0, stream>>>(d2, cand_d, cand_i);
    merge_k<<<BB, 256, 0, stream>>>(cand_d, cand_i, vals, actions, out);
}

// Round 4
// 315.651 us; speedup vs baseline: 1.6608x; 1.1584x over previous
//
#include <hip/hip_runtime.h>

#define BB 32
#define AA 8
#define NN 20000
#define DD 128
#define PP 50
#define DELTA 1e-3f
#define CH 16
#define CHUNK 1250  // NN / CH

// ---------------- conv1: [32,4,84,84] * [32,4,8,8] s4 -> [32,32,20,20] relu ----------------
__global__ __launch_bounds__(256) void conv1_k(const float* __restrict__ x,
                                               const float* __restrict__ w,
                                               const float* __restrict__ bias,
                                               float* __restrict__ y) {
    int idx = blockIdx.x * 256 + threadIdx.x;
    if (idx >= 32 * 32 * 20 * 20) return;
    int ox = idx % 20;
    int t = idx / 20;
    int oy = t % 20; t /= 20;
    int oc = t % 32;
    int b = t / 32;
    float acc = bias[oc];
    const float* xb = x + (size_t)b * 4 * 84 * 84;
    const float* wk = w + oc * 4 * 64;
    for (int ic = 0; ic < 4; ic++) {
        const float* xc = xb + ic * 84 * 84 + (oy * 4) * 84 + ox * 4;  // 16B-aligned
        const float* wc = wk + ic * 64;
#pragma unroll
        for (int ky = 0; ky < 8; ky++) {
            const float4* xr = (const float4*)(xc + ky * 84);
            const float4* wr = (const float4*)(wc + ky * 8);
            float4 x0 = xr[0], x1 = xr[1];
            float4 w0 = wr[0], w1 = wr[1];
            acc += x0.x * w0.x + x0.y * w0.y + x0.z * w0.z + x0.w * w0.w
                 + x1.x * w1.x + x1.y * w1.y + x1.z * w1.z + x1.w * w1.w;
        }
    }
    y[idx] = fmaxf(acc, 0.f);
}

// ---------------- conv2: [32,32,20,20] * [64,32,4,4] s2 -> [32,64,9,9] relu ----------------
__global__ __launch_bounds__(256) void conv2_k(const float* __restrict__ x,
                                               const float* __restrict__ w,
                                               const float* __restrict__ bias,
                                               float* __restrict__ y) {
    int idx = blockIdx.x * 256 + threadIdx.x;
    if (idx >= 32 * 64 * 9 * 9) return;
    int ox = idx % 9;
    int t = idx / 9;
    int oy = t % 9; t /= 9;
    int oc = t % 64;
    int b = t / 64;
    float acc = bias[oc];
    const float* xb = x + (size_t)b * 32 * 400;
    const float* wk = w + oc * 32 * 16;
    for (int ic = 0; ic < 32; ic++) {
        const float* xc = xb + ic * 400 + (oy * 2) * 20 + ox * 2;  // 8B-aligned
        const float* wc = wk + ic * 16;                            // 16B-aligned
#pragma unroll
        for (int ky = 0; ky < 4; ky++) {
            const float2* xr = (const float2*)(xc + ky * 20);
            float2 x0 = xr[0], x1 = xr[1];
            float4 wv = ((const float4*)(wc + ky * 4))[0];
            acc += x0.x * wv.x + x0.y * wv.y + x1.x * wv.z + x1.y * wv.w;
        }
    }
    y[idx] = fmaxf(acc, 0.f);
}

// ---------------- conv3: [32,64,9,9] * [64,64,3,3] s1 -> [32,64,7,7] relu ----------------
__global__ __launch_bounds__(256) void conv3_k(const float* __restrict__ x,
                                               const float* __restrict__ w,
                                               const float* __restrict__ bias,
                                               float* __restrict__ y) {
    int idx = blockIdx.x * 256 + threadIdx.x;
    if (idx >= 32 * 64 * 7 * 7) return;
    int ox = idx % 7;
    int t = idx / 7;
    int oy = t % 7; t /= 7;
    int oc = t % 64;
    int b = t / 64;
    float acc = bias[oc];
    const float* xb = x + (size_t)b * 64 * 81;
    const float* wk = w + oc * 64 * 9;
    for (int ic = 0; ic < 64; ic++) {
        const float* xc = xb + ic * 81 + oy * 9 + ox;
        const float* wc = wk + ic * 9;
#pragma unroll
        for (int ky = 0; ky < 3; ky++)
#pragma unroll
            for (int kx = 0; kx < 3; kx++)
                acc += xc[ky * 9 + kx] * wc[ky * 3 + kx];
    }
    y[idx] = fmaxf(acc, 0.f);
}

// ---------------- fc: [32,3136] @ [128,3136]^T + b -> h [32,128] ----------------
__global__ __launch_bounds__(256) void fc_k(const float* __restrict__ x,
                                            const float* __restrict__ w,
                                            const float* __restrict__ bias,
                                            float* __restrict__ h) {
    __shared__ float sx[3136];
    int b = blockIdx.x >> 3;
    int g = blockIdx.x & 7;
    int tid = threadIdx.x;
    const float4* xr = (const float4*)(x + (size_t)b * 3136);
    float4* sx4w = (float4*)sx;
    for (int i = tid; i < 784; i += 256) sx4w[i] = xr[i];
    __syncthreads();
    int oc_local = tid >> 4;
    int kslice = tid & 15;
    int oc = g * 16 + oc_local;
    const float4* wr = (const float4*)(w + (size_t)oc * 3136);
    const float4* sx4 = (const float4*)sx;
    float acc = 0.f;
#pragma unroll 7
    for (int j = 0; j < 49; j++) {
        int i = kslice + 16 * j;
        float4 a = sx4[i], c = wr[i];
        acc += a.x * c.x + a.y * c.y + a.z * c.z + a.w * c.w;
    }
#pragma unroll
    for (int m = 8; m >= 1; m >>= 1) acc += __shfl_xor(acc, m);
    if (kslice == 0) h[b * 128 + oc] = acc + bias[oc];
}

// ---------------- dist2: d2[b][n] = ||h[b] - keys[act[b]][n]||^2 ----------------
// grid (500, 32), block 256. Each half-wave computes 5 rows, all loads issued up-front.
__global__ __launch_bounds__(256) void dist2_k(const float* __restrict__ h,
                                               const int* __restrict__ actions,
                                               const float* __restrict__ keys,
                                               float* __restrict__ d2) {
    int b = blockIdx.y;
    int a = actions[b];
    int tid = threadIdx.x;
    int hw = tid >> 5;       // half-wave 0..7
    int l32 = tid & 31;
    float4 hv = ((const float4*)(h + b * DD))[l32];
    const float* kb = keys + (size_t)a * NN * DD;
    int r0 = blockIdx.x * 40 + hw * 5;
    float s0, s1, s2, s3, s4;
    {
        float4 k0 = ((const float4*)(kb + (size_t)(r0 + 0) * DD))[l32];
        float4 k1 = ((const float4*)(kb + (size_t)(r0 + 1) * DD))[l32];
        float4 k2 = ((const float4*)(kb + (size_t)(r0 + 2) * DD))[l32];
        float4 k3 = ((const float4*)(kb + (size_t)(r0 + 3) * DD))[l32];
        float4 k4 = ((const float4*)(kb + (size_t)(r0 + 4) * DD))[l32];
        float dx, dy, dz, dw;
        dx = hv.x - k0.x; dy = hv.y - k0.y; dz = hv.z - k0.z; dw = hv.w - k0.w;
        s0 = dx * dx + dy * dy + dz * dz + dw * dw;
        dx = hv.x - k1.x; dy = hv.y - k1.y; dz = hv.z - k1.z; dw = hv.w - k1.w;
        s1 = dx * dx + dy * dy + dz * dz + dw * dw;
        dx = hv.x - k2.x; dy = hv.y - k2.y; dz = hv.z - k2.z; dw = hv.w - k2.w;
        s2 = dx * dx + dy * dy + dz * dz + dw * dw;
        dx = hv.x - k3.x; dy = hv.y - k3.y; dz = hv.z - k3.z; dw = hv.w - k3.w;
        s3 = dx * dx + dy * dy + dz * dz + dw * dw;
        dx = hv.x - k4.x; dy = hv.y - k4.y; dz = hv.z - k4.z; dw = hv.w - k4.w;
        s4 = dx * dx + dy * dy + dz * dz + dw * dw;
    }
#pragma unroll
    for (int m = 16; m >= 1; m >>= 1) {
        s0 += __shfl_xor(s0, m);
        s1 += __shfl_xor(s1, m);
        s2 += __shfl_xor(s2, m);
        s3 += __shfl_xor(s3, m);
        s4 += __shfl_xor(s4, m);
    }
    if (l32 == 0) {
        float* dst = d2 + (size_t)b * NN + r0;
        dst[0] = s0; dst[1] = s1; dst[2] = s2; dst[3] = s3; dst[4] = s4;
    }
}

// ---------------- sel: per-chunk stable top-50 via parallel rank-counting ----------------
// grid (CH, B), block 256. key = (f32bits(d) << 32) | idx  -> exact stable order.
// rank(i) = #{j : key_j < key_i}; rank < 50 => selected, rank is the output slot.
__global__ __launch_bounds__(256) void sel_k(const float* __restrict__ d2,
                                             float* __restrict__ cand_d,
                                             int* __restrict__ cand_i) {
    int b = blockIdx.y;
    int chunk = blockIdx.x;
    int r0 = chunk * CHUNK;
    int tid = threadIdx.x;
    __shared__ __align__(16) float sd[CHUNK + 2];
    const float* src = d2 + (size_t)b * NN + r0;
    for (int i = tid; i < CHUNK; i += 256) sd[i] = src[i];
    __syncthreads();

    // 5 owned elements: i = tid + 256*k (k=4 valid only for tid < 226)
    unsigned long long k0, k1, k2, k3, k4;
    int i0 = tid, i1 = tid + 256, i2 = tid + 512, i3 = tid + 768, i4 = tid + 1024;
    k0 = ((unsigned long long)__float_as_uint(sd[i0]) << 32) | (unsigned)i0;
    k1 = ((unsigned long long)__float_as_uint(sd[i1]) << 32) | (unsigned)i1;
    k2 = ((unsigned long long)__float_as_uint(sd[i2]) << 32) | (unsigned)i2;
    k3 = ((unsigned long long)__float_as_uint(sd[i3]) << 32) | (unsigned)i3;
    k4 = (i4 < CHUNK)
           ? (((unsigned long long)__float_as_uint(sd[i4]) << 32) | (unsigned)i4)
           : 0xFFFFFFFFFFFFFFFFULL;  // pad: never selected
    int c0 = 0, c1 = 0, c2 = 0, c3 = 0, c4 = 0;

    const float4* sd4 = (const float4*)sd;
#pragma unroll 2
    for (int g = 0; g < CHUNK / 4; g++) {  // j = 0..1247
        float4 v = sd4[g];
        unsigned j0 = (unsigned)(g * 4);
        unsigned long long kj;
        kj = ((unsigned long long)__float_as_uint(v.x) << 32) | (j0 + 0);
        c0 += (kj < k0); c1 += (kj < k1); c2 += (kj < k2); c3 += (kj < k3); c4 += (kj < k4);
        kj = ((unsigned long long)__float_as_uint(v.y) << 32) | (j0 + 1);
        c0 += (kj < k0); c1 += (kj < k1); c2 += (kj < k2); c3 += (kj < k3); c4 += (kj < k4);
        kj = ((unsigned long long)__float_as_uint(v.z) << 32) | (j0 + 2);
        c0 += (kj < k0); c1 += (kj < k1); c2 += (kj < k2); c3 += (kj < k3); c4 += (kj < k4);
        kj = ((unsigned long long)__float_as_uint(v.w) << 32) | (j0 + 3);
        c0 += (kj < k0); c1 += (kj < k1); c2 += (kj < k2); c3 += (kj < k3); c4 += (kj < k4);
    }
    // remainder j = 1248, 1249
#pragma unroll
    for (int j = CHUNK & ~3; j < CHUNK; j++) {
        unsigned long long kj = ((unsigned long long)__float_as_uint(sd[j]) << 32) | (unsigned)j;
        c0 += (kj < k0); c1 += (kj < k1); c2 += (kj < k2); c3 += (kj < k3); c4 += (kj < k4);
    }

    float* cd = cand_d + ((size_t)b * CH + chunk) * PP;
    int* ci = cand_i + ((size_t)b * CH + chunk) * PP;
    if (c0 < PP) { cd[c0] = __uint_as_float((unsigned)(k0 >> 32)); ci[c0] = r0 + i0; }
    if (c1 < PP) { cd[c1] = __uint_as_float((unsigned)(k1 >> 32)); ci[c1] = r0 + i1; }
    if (c2 < PP) { cd[c2] = __uint_as_float((unsigned)(k2 >> 32)); ci[c2] = r0 + i2; }
    if (c3 < PP) { cd[c3] = __uint_as_float((unsigned)(k3 >> 32)); ci[c3] = r0 + i3; }
    if (c4 < PP) { cd[c4] = __uint_as_float((unsigned)(k4 >> 32)); ci[c4] = r0 + i4; }
}

// ---------------- merge: 800 candidates -> global rank-count top-50 -> weighted sum ----------------
// Per-chunk candidates are exact per-chunk top-50 => any global-top-50 element is present,
// and every element smaller than it is also present => candidate-rank == global rank.
__global__ __launch_bounds__(1024) void merge_k(const float* __restrict__ cand_d,
                                                const int* __restrict__ cand_i,
                                                const float* __restrict__ values,
                                                const int* __restrict__ actions,
                                                float* __restrict__ q) {
    const int M = CH * PP;  // 800
    int b = blockIdx.x, tid = threadIdx.x;
    int lane = tid & 63, wave = tid >> 6;
    __shared__ __align__(16) float md[M];
    __shared__ __align__(16) int mi[M];
    __shared__ float sw[16], swv[16];
    if (tid < M) {
        md[tid] = cand_d[(size_t)b * M + tid];
        mi[tid] = cand_i[(size_t)b * M + tid];
    }
    __syncthreads();

    float w = 0.f, wv = 0.f;
    if (tid < M) {
        float dmy = md[tid];
        unsigned long long km = ((unsigned long long)__float_as_uint(dmy) << 32) | (unsigned)mi[tid];
        int cnt = 0;
        const float4* md4 = (const float4*)md;
        const int4* mi4 = (const int4*)mi;
        for (int g = 0; g < M / 4; g++) {  // 200 groups
            float4 v = md4[g];
            int4 gi = mi4[g];
            unsigned long long kj;
            kj = ((unsigned long long)__float_as_uint(v.x) << 32) | (unsigned)gi.x; cnt += (kj < km);
            kj = ((unsigned long long)__float_as_uint(v.y) << 32) | (unsigned)gi.y; cnt += (kj < km);
            kj = ((unsigned long long)__float_as_uint(v.z) << 32) | (unsigned)gi.z; cnt += (kj < km);
            kj = ((unsigned long long)__float_as_uint(v.w) << 32) | (unsigned)gi.w; cnt += (kj < km);
        }
        if (cnt < PP) {
            int a = actions[b];
            float dd = fmaxf(dmy, 0.f);
            w = 1.f / (dd + DELTA);
            wv = w * values[(size_t)a * NN + mi[tid]];
        }
    }
#pragma unroll
    for (int m = 32; m >= 1; m >>= 1) {
        w += __shfl_xor(w, m);
        wv += __shfl_xor(wv, m);
    }
    if (lane == 0) { sw[wave] = w; swv[wave] = wv; }
    __syncthreads();
    if (tid < 16) {
        float tw = sw[tid], twv = swv[tid];
#pragma unroll
        for (int m = 8; m >= 1; m >>= 1) {
            tw += __shfl_xor(tw, m);
            twv += __shfl_xor(twv, m);
        }
        if (tid == 0) q[b] = twv / tw;
    }
}

extern "C" void kernel_launch(void* const* d_in, const int* in_sizes, int n_in,
                              void* d_out, int out_size, void* d_ws, size_t ws_size,
                              hipStream_t stream) {
    const float* states = (const float*)d_in[0];
    const int* actions = (const int*)d_in[1];
    const float* c1w = (const float*)d_in[2];
    const float* c1b = (const float*)d_in[3];
    const float* c2w = (const float*)d_in[4];
    const float* c2b = (const float*)d_in[5];
    const float* c3w = (const float*)d_in[6];
    const float* c3b = (const float*)d_in[7];
    const float* fcw = (const float*)d_in[8];
    const float* fcb = (const float*)d_in[9];
    const float* keys = (const float*)d_in[10];
    const float* vals = (const float*)d_in[11];
    float* out = (float*)d_out;

    float* ws = (float*)d_ws;
    float* c1o = ws;                    // 409600 (dead after conv2 -> reused for cand_*)
    float* c2o = c1o + 409600;          // 165888
    float* c3o = c2o + 165888;          // 100352
    float* h   = c3o + 100352;          // 4096
    float* d2  = h + 4096;              // 640000
    float* cand_d = ws;                 // 25600 (overlaps dead c1o)
    int* cand_i = (int*)(cand_d + 25600);  // 25600

    conv1_k<<<(409600 + 255) / 256, 256, 0, stream>>>(states, c1w, c1b, c1o);
    conv2_k<<<(165888 + 255) / 256, 256, 0, stream>>>(c1o, c2w, c2b, c2o);
    conv3_k<<<(100352 + 255) / 256, 256, 0, stream>>>(c2o, c3w, c3b, c3o);
    fc_k<<<256, 256, 0, stream>>>(c3o, fcw, fcb, h);
    dist2_k<<<dim3(500, BB), 256, 0, stream>>>(h, actions, keys, d2);
    sel_k<<<dim3(CH, BB), 256, 0, stream>>>(d2, cand_d, cand_i);
    merge_k<<<BB, 1024, 0, stream>>>(cand_d, cand_i, vals, actions, out);
}

// Round 5
// 257.336 us; speedup vs baseline: 2.0371x; 1.2266x over previous
//
#include <hip/hip_runtime.h>

#define BB 32
#define AA 8
#define NN 20000
#define DD 128
#define PP 50
#define DELTA 1e-3f

typedef unsigned long long ull;

// ---------------- conv1: [32,4,84,84] * [32,4,8,8] s4 -> [32,32,20,20] relu ----------------
__global__ __launch_bounds__(256) void conv1_k(const float* __restrict__ x,
                                               const float* __restrict__ w,
                                               const float* __restrict__ bias,
                                               float* __restrict__ y) {
    int idx = blockIdx.x * 256 + threadIdx.x;
    if (idx >= 32 * 32 * 20 * 20) return;
    int ox = idx % 20;
    int t = idx / 20;
    int oy = t % 20; t /= 20;
    int oc = t % 32;
    int b = t / 32;
    float acc = bias[oc];
    const float* xb = x + (size_t)b * 4 * 84 * 84;
    const float* wk = w + oc * 4 * 64;
    for (int ic = 0; ic < 4; ic++) {
        const float* xc = xb + ic * 84 * 84 + (oy * 4) * 84 + ox * 4;  // 16B-aligned
        const float* wc = wk + ic * 64;
#pragma unroll
        for (int ky = 0; ky < 8; ky++) {
            const float4* xr = (const float4*)(xc + ky * 84);
            const float4* wr = (const float4*)(wc + ky * 8);
            float4 x0 = xr[0], x1 = xr[1];
            float4 w0 = wr[0], w1 = wr[1];
            acc += x0.x * w0.x + x0.y * w0.y + x0.z * w0.z + x0.w * w0.w
                 + x1.x * w1.x + x1.y * w1.y + x1.z * w1.z + x1.w * w1.w;
        }
    }
    y[idx] = fmaxf(acc, 0.f);
}

// ---------------- conv2: [32,32,20,20] * [64,32,4,4] s2 -> [32,64,9,9] relu ----------------
__global__ __launch_bounds__(256) void conv2_k(const float* __restrict__ x,
                                               const float* __restrict__ w,
                                               const float* __restrict__ bias,
                                               float* __restrict__ y) {
    int idx = blockIdx.x * 256 + threadIdx.x;
    if (idx >= 32 * 64 * 9 * 9) return;
    int ox = idx % 9;
    int t = idx / 9;
    int oy = t % 9; t /= 9;
    int oc = t % 64;
    int b = t / 64;
    float acc = bias[oc];
    const float* xb = x + (size_t)b * 32 * 400;
    const float* wk = w + oc * 32 * 16;
    for (int ic = 0; ic < 32; ic++) {
        const float* xc = xb + ic * 400 + (oy * 2) * 20 + ox * 2;  // 8B-aligned
        const float* wc = wk + ic * 16;                            // 16B-aligned
#pragma unroll
        for (int ky = 0; ky < 4; ky++) {
            const float2* xr = (const float2*)(xc + ky * 20);
            float2 x0 = xr[0], x1 = xr[1];
            float4 wv = ((const float4*)(wc + ky * 4))[0];
            acc += x0.x * wv.x + x0.y * wv.y + x1.x * wv.z + x1.y * wv.w;
        }
    }
    y[idx] = fmaxf(acc, 0.f);
}

// ---------------- conv3: [32,64,9,9] * [64,64,3,3] s1 -> [32,64,7,7] relu ----------------
__global__ __launch_bounds__(256) void conv3_k(const float* __restrict__ x,
                                               const float* __restrict__ w,
                                               const float* __restrict__ bias,
                                               float* __restrict__ y) {
    int idx = blockIdx.x * 256 + threadIdx.x;
    if (idx >= 32 * 64 * 7 * 7) return;
    int ox = idx % 7;
    int t = idx / 7;
    int oy = t % 7; t /= 7;
    int oc = t % 64;
    int b = t / 64;
    float acc = bias[oc];
    const float* xb = x + (size_t)b * 64 * 81;
    const float* wk = w + oc * 64 * 9;
    for (int ic = 0; ic < 64; ic++) {
        const float* xc = xb + ic * 81 + oy * 9 + ox;
        const float* wc = wk + ic * 9;
#pragma unroll
        for (int ky = 0; ky < 3; ky++)
#pragma unroll
            for (int kx = 0; kx < 3; kx++)
                acc += xc[ky * 9 + kx] * wc[ky * 3 + kx];
    }
    y[idx] = fmaxf(acc, 0.f);
}

// ---------------- fc: [32,3136] @ [128,3136]^T + b -> h [32,128] ----------------
__global__ __launch_bounds__(256) void fc_k(const float* __restrict__ x,
                                            const float* __restrict__ w,
                                            const float* __restrict__ bias,
                                            float* __restrict__ h) {
    __shared__ float sx[3136];
    int b = blockIdx.x >> 3;
    int g = blockIdx.x & 7;
    int tid = threadIdx.x;
    const float4* xr = (const float4*)(x + (size_t)b * 3136);
    float4* sx4w = (float4*)sx;
    for (int i = tid; i < 784; i += 256) sx4w[i] = xr[i];
    __syncthreads();
    int oc_local = tid >> 4;
    int kslice = tid & 15;
    int oc = g * 16 + oc_local;
    const float4* wr = (const float4*)(w + (size_t)oc * 3136);
    const float4* sx4 = (const float4*)sx;
    float acc = 0.f;
#pragma unroll 7
    for (int j = 0; j < 49; j++) {
        int i = kslice + 16 * j;
        float4 a = sx4[i], c = wr[i];
        acc += a.x * c.x + a.y * c.y + a.z * c.z + a.w * c.w;
    }
#pragma unroll
    for (int m = 8; m >= 1; m >>= 1) acc += __shfl_xor(acc, m);
    if (kslice == 0) h[b * 128 + oc] = acc + bias[oc];
}

// ---------------- dist2: d2[b][n] = ||h[b] - keys[act[b]][n]||^2 ----------------
// grid (500, 32), block 256. Each half-wave computes 5 rows, all loads issued up-front.
__global__ __launch_bounds__(256) void dist2_k(const float* __restrict__ h,
                                               const int* __restrict__ actions,
                                               const float* __restrict__ keys,
                                               float* __restrict__ d2) {
    int b = blockIdx.y;
    int a = actions[b];
    int tid = threadIdx.x;
    int hw = tid >> 5;       // half-wave 0..7
    int l32 = tid & 31;
    float4 hv = ((const float4*)(h + b * DD))[l32];
    const float* kb = keys + (size_t)a * NN * DD;
    int r0 = blockIdx.x * 40 + hw * 5;
    float s0, s1, s2, s3, s4;
    {
        float4 k0 = ((const float4*)(kb + (size_t)(r0 + 0) * DD))[l32];
        float4 k1 = ((const float4*)(kb + (size_t)(r0 + 1) * DD))[l32];
        float4 k2 = ((const float4*)(kb + (size_t)(r0 + 2) * DD))[l32];
        float4 k3 = ((const float4*)(kb + (size_t)(r0 + 3) * DD))[l32];
        float4 k4 = ((const float4*)(kb + (size_t)(r0 + 4) * DD))[l32];
        float dx, dy, dz, dw;
        dx = hv.x - k0.x; dy = hv.y - k0.y; dz = hv.z - k0.z; dw = hv.w - k0.w;
        s0 = dx * dx + dy * dy + dz * dz + dw * dw;
        dx = hv.x - k1.x; dy = hv.y - k1.y; dz = hv.z - k1.z; dw = hv.w - k1.w;
        s1 = dx * dx + dy * dy + dz * dz + dw * dw;
        dx = hv.x - k2.x; dy = hv.y - k2.y; dz = hv.z - k2.z; dw = hv.w - k2.w;
        s2 = dx * dx + dy * dy + dz * dz + dw * dw;
        dx = hv.x - k3.x; dy = hv.y - k3.y; dz = hv.z - k3.z; dw = hv.w - k3.w;
        s3 = dx * dx + dy * dy + dz * dz + dw * dw;
        dx = hv.x - k4.x; dy = hv.y - k4.y; dz = hv.z - k4.z; dw = hv.w - k4.w;
        s4 = dx * dx + dy * dy + dz * dz + dw * dw;
    }
#pragma unroll
    for (int m = 16; m >= 1; m >>= 1) {
        s0 += __shfl_xor(s0, m);
        s1 += __shfl_xor(s1, m);
        s2 += __shfl_xor(s2, m);
        s3 += __shfl_xor(s3, m);
        s4 += __shfl_xor(s4, m);
    }
    if (l32 == 0) {
        float* dst = d2 + (size_t)b * NN + r0;
        dst[0] = s0; dst[1] = s1; dst[2] = s2; dst[3] = s3; dst[4] = s4;
    }
}

// ---------------- select: fused exact top-50 (two-level radix on float bits) + weighted sum ----
// d2 >= 0 so float bits are order-isomorphic. key = (bits << 32) | idx reproduces lax.top_k's
// stable (lowest-index-on-tie) order exactly. grid BB, block 1024.
__global__ __launch_bounds__(1024) void select_k(const float* __restrict__ d2,
                                                 const float* __restrict__ values,
                                                 const int* __restrict__ actions,
                                                 float* __restrict__ q) {
    const int NB = 8160;   // coarse buckets: bits >> 18 (covers all finite floats)
    const int CAP = 512;
    int b = blockIdx.x, tid = threadIdx.x;
    int lane = tid & 63, wave = tid >> 6;  // 16 waves
    __shared__ int hist[NB];
    __shared__ int fhist[1024];
    __shared__ float cd[CAP];
    __shared__ int ci[CAP];
    __shared__ int scounter;
    __shared__ int s_t, s_below;
    __shared__ int s_ft;
    __shared__ int wsum[16];
    __shared__ float rw[16], rwv[16];

    const float* db = d2 + (size_t)b * NN;
    for (int i = tid; i < NB; i += 1024) hist[i] = 0;
    fhist[tid] = 0;
    if (tid == 0) scounter = 0;
    __syncthreads();

    // ---- pass 1: coarse histogram ----
    for (int i = tid; i < NN; i += 1024)
        atomicAdd(&hist[__float_as_uint(db[i]) >> 18], 1);
    __syncthreads();

    // ---- find coarse cutoff bucket t: smallest t with cum(t) >= PP ----
    {
        int s = 0;
#pragma unroll
        for (int u = 0; u < 8; u++) s += hist[tid * 8 + u];  // strip [8*tid, 8*tid+8), 8192>=NB ok
        int sc = s;
#pragma unroll
        for (int m = 1; m < 64; m <<= 1) {
            int o = __shfl_up(sc, m);
            if (lane >= m) sc += o;
        }
        if (lane == 63) wsum[wave] = sc;
        __syncthreads();
        if (tid < 16) {
            int vc = wsum[tid];
            for (int m = 1; m < 16; m <<= 1) {
                int o = __shfl_up(vc, m);
                if (tid >= m) vc += o;
            }
            wsum[tid] = vc;
        }
        __syncthreads();
        int incl = ((wave == 0) ? 0 : wsum[wave - 1]) + sc;
        int excl = incl - s;
        if (excl < PP && incl >= PP) {  // exactly one strip crosses
            int c = excl;
#pragma unroll
            for (int u = 0; u < 8; u++) {
                int bkt = tid * 8 + u;
                int hv = hist[bkt];
                if (c < PP && c + hv >= PP) { s_t = bkt; s_below = c; }
                c += hv;
            }
        }
    }
    __syncthreads();
    int t = s_t, below = s_below;

    // ---- pass 2: fine histogram (next 10 bits) within bucket t ----
    for (int i = tid; i < NN; i += 1024) {
        unsigned bits = __float_as_uint(db[i]);
        if ((int)(bits >> 18) == t) atomicAdd(&fhist[(bits >> 8) & 1023], 1);
    }
    __syncthreads();

    // ---- find fine cutoff ft: smallest with below + finecum(ft) >= PP ----
    {
        int s = fhist[tid];
        int sc = s;
#pragma unroll
        for (int m = 1; m < 64; m <<= 1) {
            int o = __shfl_up(sc, m);
            if (lane >= m) sc += o;
        }
        if (lane == 63) wsum[wave] = sc;
        __syncthreads();
        if (tid < 16) {
            int vc = wsum[tid];
            for (int m = 1; m < 16; m <<= 1) {
                int o = __shfl_up(vc, m);
                if (tid >= m) vc += o;
            }
            wsum[tid] = vc;
        }
        __syncthreads();
        int incl = ((wave == 0) ? 0 : wsum[wave - 1]) + sc;
        int excl = incl - s;
        if (below + excl < PP && below + incl >= PP) s_ft = tid;
    }
    __syncthreads();
    int ft = s_ft;

    // ---- pass 3: collect superset of top-PP (bounded: <50 strictly below cutoff + ties at cutoff) ----
    for (int i = tid; i < NN; i += 1024) {
        unsigned bits = __float_as_uint(db[i]);
        int c = (int)(bits >> 18);
        bool take = (c < t) || (c == t && (int)((bits >> 8) & 1023) <= ft);
        if (take) {
            int slot = atomicAdd(&scounter, 1);
            if (slot < CAP) { cd[slot] = db[i]; ci[slot] = i; }
        }
    }
    __syncthreads();
    int k = min(scounter, CAP);

    // ---- exact stable rank-count on k (~60) elements + weighted sum ----
    float w = 0.f, wv = 0.f;
    int a = actions[b];
    for (int s = tid; s < k; s += 1024) {
        ull key = ((ull)__float_as_uint(cd[s]) << 32) | (unsigned)ci[s];
        int cnt = 0;
        for (int j = 0; j < k; j++) {
            ull kj = ((ull)__float_as_uint(cd[j]) << 32) | (unsigned)ci[j];
            cnt += (kj < key);
        }
        if (cnt < PP) {
            float dd = fmaxf(cd[s], 0.f);
            float ww = 1.f / (dd + DELTA);
            w += ww;
            wv += ww * values[(size_t)a * NN + ci[s]];
        }
    }
#pragma unroll
    for (int m = 32; m >= 1; m >>= 1) {
        w += __shfl_xor(w, m);
        wv += __shfl_xor(wv, m);
    }
    if (lane == 0) { rw[wave] = w; rwv[wave] = wv; }
    __syncthreads();
    if (tid < 16) {
        float tw = rw[tid], twv = rwv[tid];
#pragma unroll
        for (int m = 8; m >= 1; m >>= 1) {
            tw += __shfl_xor(tw, m);
            twv += __shfl_xor(twv, m);
        }
        if (tid == 0) q[b] = twv / tw;
    }
}

extern "C" void kernel_launch(void* const* d_in, const int* in_sizes, int n_in,
                              void* d_out, int out_size, void* d_ws, size_t ws_size,
                              hipStream_t stream) {
    const float* states = (const float*)d_in[0];
    const int* actions = (const int*)d_in[1];
    const float* c1w = (const float*)d_in[2];
    const float* c1b = (const float*)d_in[3];
    const float* c2w = (const float*)d_in[4];
    const float* c2b = (const float*)d_in[5];
    const float* c3w = (const float*)d_in[6];
    const float* c3b = (const float*)d_in[7];
    const float* fcw = (const float*)d_in[8];
    const float* fcb = (const float*)d_in[9];
    const float* keys = (const float*)d_in[10];
    const float* vals = (const float*)d_in[11];
    float* out = (float*)d_out;

    float* ws = (float*)d_ws;
    float* c1o = ws;                    // 409600
    float* c2o = c1o + 409600;          // 165888
    float* c3o = c2o + 165888;          // 100352
    float* h   = c3o + 100352;          // 4096
    float* d2  = h + 4096;              // 640000

    conv1_k<<<(409600 + 255) / 256, 256, 0, stream>>>(states, c1w, c1b, c1o);
    conv2_k<<<(165888 + 255) / 256, 256, 0, stream>>>(c1o, c2w, c2b, c2o);
    conv3_k<<<(100352 + 255) / 256, 256, 0, stream>>>(c2o, c3w, c3b, c3o);
    fc_k<<<256, 256, 0, stream>>>(c3o, fcw, fcb, h);
    dist2_k<<<dim3(500, BB), 256, 0, stream>>>(h, actions, keys, d2);
    select_k<<<BB, 1024, 0, stream>>>(d2, vals, actions, out);
}

// Round 6
// 247.723 us; speedup vs baseline: 2.1162x; 1.0388x over previous
//
#include <hip/hip_runtime.h>

#define BB 32
#define AA 8
#define NN 20000
#define DD 128
#define PP 50
#define DELTA 1e-3f

typedef unsigned long long ull;

// ---------------- conv1: [32,4,84,84] * [32,4,8,8] s4 -> [32,32,20,20] relu ----------------
__global__ __launch_bounds__(256) void conv1_k(const float* __restrict__ x,
                                               const float* __restrict__ w,
                                               const float* __restrict__ bias,
                                               float* __restrict__ y) {
    int idx = blockIdx.x * 256 + threadIdx.x;
    if (idx >= 32 * 32 * 20 * 20) return;
    int ox = idx % 20;
    int t = idx / 20;
    int oy = t % 20; t /= 20;
    int oc = t % 32;
    int b = t / 32;
    float acc = bias[oc];
    const float* xb = x + (size_t)b * 4 * 84 * 84;
    const float* wk = w + oc * 4 * 64;
    for (int ic = 0; ic < 4; ic++) {
        const float* xc = xb + ic * 84 * 84 + (oy * 4) * 84 + ox * 4;  // 16B-aligned
        const float* wc = wk + ic * 64;
#pragma unroll
        for (int ky = 0; ky < 8; ky++) {
            const float4* xr = (const float4*)(xc + ky * 84);
            const float4* wr = (const float4*)(wc + ky * 8);
            float4 x0 = xr[0], x1 = xr[1];
            float4 w0 = wr[0], w1 = wr[1];
            acc += x0.x * w0.x + x0.y * w0.y + x0.z * w0.z + x0.w * w0.w
                 + x1.x * w1.x + x1.y * w1.y + x1.z * w1.z + x1.w * w1.w;
        }
    }
    y[idx] = fmaxf(acc, 0.f);
}

// ---------------- conv2: [32,32,20,20] * [64,32,4,4] s2 -> [32,64,9,9] relu ----------------
__global__ __launch_bounds__(256) void conv2_k(const float* __restrict__ x,
                                               const float* __restrict__ w,
                                               const float* __restrict__ bias,
                                               float* __restrict__ y) {
    int idx = blockIdx.x * 256 + threadIdx.x;
    if (idx >= 32 * 64 * 9 * 9) return;
    int ox = idx % 9;
    int t = idx / 9;
    int oy = t % 9; t /= 9;
    int oc = t % 64;
    int b = t / 64;
    float acc = bias[oc];
    const float* xb = x + (size_t)b * 32 * 400;
    const float* wk = w + oc * 32 * 16;
    for (int ic = 0; ic < 32; ic++) {
        const float* xc = xb + ic * 400 + (oy * 2) * 20 + ox * 2;  // 8B-aligned
        const float* wc = wk + ic * 16;                            // 16B-aligned
#pragma unroll
        for (int ky = 0; ky < 4; ky++) {
            const float2* xr = (const float2*)(xc + ky * 20);
            float2 x0 = xr[0], x1 = xr[1];
            float4 wv = ((const float4*)(wc + ky * 4))[0];
            acc += x0.x * wv.x + x0.y * wv.y + x1.x * wv.z + x1.y * wv.w;
        }
    }
    y[idx] = fmaxf(acc, 0.f);
}

// ---------------- conv3: [32,64,9,9] * [64,64,3,3] s1 -> [32,64,7,7] relu ----------------
__global__ __launch_bounds__(256) void conv3_k(const float* __restrict__ x,
                                               const float* __restrict__ w,
                                               const float* __restrict__ bias,
                                               float* __restrict__ y) {
    int idx = blockIdx.x * 256 + threadIdx.x;
    if (idx >= 32 * 64 * 7 * 7) return;
    int ox = idx % 7;
    int t = idx / 7;
    int oy = t % 7; t /= 7;
    int oc = t % 64;
    int b = t / 64;
    float acc = bias[oc];
    const float* xb = x + (size_t)b * 64 * 81;
    const float* wk = w + oc * 64 * 9;
    for (int ic = 0; ic < 64; ic++) {
        const float* xc = xb + ic * 81 + oy * 9 + ox;
        const float* wc = wk + ic * 9;
#pragma unroll
        for (int ky = 0; ky < 3; ky++)
#pragma unroll
            for (int kx = 0; kx < 3; kx++)
                acc += xc[ky * 9 + kx] * wc[ky * 3 + kx];
    }
    y[idx] = fmaxf(acc, 0.f);
}

// ---------------- fc: [32,3136] @ [128,3136]^T + b -> h [32,128] ----------------
__global__ __launch_bounds__(256) void fc_k(const float* __restrict__ x,
                                            const float* __restrict__ w,
                                            const float* __restrict__ bias,
                                            float* __restrict__ h) {
    __shared__ float sx[3136];
    int b = blockIdx.x >> 3;
    int g = blockIdx.x & 7;
    int tid = threadIdx.x;
    const float4* xr = (const float4*)(x + (size_t)b * 3136);
    float4* sx4w = (float4*)sx;
    for (int i = tid; i < 784; i += 256) sx4w[i] = xr[i];
    __syncthreads();
    int oc_local = tid >> 4;
    int kslice = tid & 15;
    int oc = g * 16 + oc_local;
    const float4* wr = (const float4*)(w + (size_t)oc * 3136);
    const float4* sx4 = (const float4*)sx;
    float acc = 0.f;
#pragma unroll 7
    for (int j = 0; j < 49; j++) {
        int i = kslice + 16 * j;
        float4 a = sx4[i], c = wr[i];
        acc += a.x * c.x + a.y * c.y + a.z * c.z + a.w * c.w;
    }
#pragma unroll
    for (int m = 8; m >= 1; m >>= 1) acc += __shfl_xor(acc, m);
    if (kslice == 0) h[b * 128 + oc] = acc + bias[oc];
}

// ---------------- route: per-action sample lists via ballot ----------------
__global__ __launch_bounds__(64) void route_k(const int* __restrict__ actions,
                                              int* __restrict__ cnt,
                                              int* __restrict__ list) {
    int lane = threadIdx.x;
    int act = (lane < BB) ? actions[lane] : -1;
#pragma unroll
    for (int a = 0; a < AA; a++) {
        ull mask = __ballot(act == a);
        if (act == a) {
            int pos = __popcll(mask & ((1ull << lane) - 1));
            list[a * BB + pos] = lane;
        }
        if (lane == a) cnt[a] = __popcll(mask);
    }
}

// ---------------- dist3: action-grouped distances; key rows read once ----------------
// grid (125, AA), block 256. 160 rows/block, 8 half-waves x 20 rows.
// Each half-wave loads 5 key rows (float4/lane), then loops the action's m samples
// (h vectors LDS-resident), reducing 5 distances per sample via shuffles.
__global__ __launch_bounds__(256) void dist3_k(const float* __restrict__ h,
                                               const int* __restrict__ cnt,
                                               const int* __restrict__ list,
                                               const float* __restrict__ keys,
                                               float* __restrict__ d2) {
    int a = blockIdx.y;
    int m = cnt[a];
    if (m == 0) return;
    int tid = threadIdx.x;
    __shared__ float hl[BB * DD];
    __shared__ int sl[BB];
    if (tid < BB) sl[tid] = list[a * BB + tid];
    __syncthreads();
    for (int i = tid; i < m * DD; i += 256) {
        int j = i >> 7;
        hl[i] = h[sl[j] * DD + (i & 127)];
    }
    __syncthreads();

    int hw = tid >> 5;   // half-wave 0..7
    int l32 = tid & 31;
    const float* kb = keys + (size_t)a * NN * DD;
    const float4* hl4 = (const float4*)hl;
    int r0 = blockIdx.x * 160 + hw * 20;

    for (int rr = 0; rr < 20; rr += 5) {
        int r = r0 + rr;
        float4 k0 = ((const float4*)(kb + (size_t)(r + 0) * DD))[l32];
        float4 k1 = ((const float4*)(kb + (size_t)(r + 1) * DD))[l32];
        float4 k2 = ((const float4*)(kb + (size_t)(r + 2) * DD))[l32];
        float4 k3 = ((const float4*)(kb + (size_t)(r + 3) * DD))[l32];
        float4 k4 = ((const float4*)(kb + (size_t)(r + 4) * DD))[l32];
        for (int j = 0; j < m; j++) {
            float4 hv = hl4[j * 32 + l32];
            float dx, dy, dz, dw, s0, s1, s2, s3, s4;
            dx = hv.x - k0.x; dy = hv.y - k0.y; dz = hv.z - k0.z; dw = hv.w - k0.w;
            s0 = dx * dx + dy * dy + dz * dz + dw * dw;
            dx = hv.x - k1.x; dy = hv.y - k1.y; dz = hv.z - k1.z; dw = hv.w - k1.w;
            s1 = dx * dx + dy * dy + dz * dz + dw * dw;
            dx = hv.x - k2.x; dy = hv.y - k2.y; dz = hv.z - k2.z; dw = hv.w - k2.w;
            s2 = dx * dx + dy * dy + dz * dz + dw * dw;
            dx = hv.x - k3.x; dy = hv.y - k3.y; dz = hv.z - k3.z; dw = hv.w - k3.w;
            s3 = dx * dx + dy * dy + dz * dz + dw * dw;
            dx = hv.x - k4.x; dy = hv.y - k4.y; dz = hv.z - k4.z; dw = hv.w - k4.w;
            s4 = dx * dx + dy * dy + dz * dz + dw * dw;
#pragma unroll
            for (int mm = 16; mm >= 1; mm >>= 1) {
                s0 += __shfl_xor(s0, mm);
                s1 += __shfl_xor(s1, mm);
                s2 += __shfl_xor(s2, mm);
                s3 += __shfl_xor(s3, mm);
                s4 += __shfl_xor(s4, mm);
            }
            if (l32 == 0) {
                float* dst = d2 + (size_t)sl[j] * NN + r;
                dst[0] = s0; dst[1] = s1; dst[2] = s2; dst[3] = s3; dst[4] = s4;
            }
        }
    }
}

// ---------------- select: fused exact top-50 (two-level radix on float bits) + weighted sum ----
// d2 >= 0 so float bits are order-isomorphic. key = (bits << 32) | idx reproduces lax.top_k's
// stable (lowest-index-on-tie) order exactly. grid BB, block 1024.
__global__ __launch_bounds__(1024) void select_k(const float* __restrict__ d2,
                                                 const float* __restrict__ values,
                                                 const int* __restrict__ actions,
                                                 float* __restrict__ q) {
    const int NB = 8160;   // coarse buckets: bits >> 18 (covers all finite floats)
    const int CAP = 512;
    int b = blockIdx.x, tid = threadIdx.x;
    int lane = tid & 63, wave = tid >> 6;  // 16 waves
    __shared__ int hist[NB];
    __shared__ int fhist[1024];
    __shared__ float cd[CAP];
    __shared__ int ci[CAP];
    __shared__ int scounter;
    __shared__ int s_t, s_below;
    __shared__ int s_ft;
    __shared__ int wsum[16];
    __shared__ float rw[16], rwv[16];

    const float* db = d2 + (size_t)b * NN;
    for (int i = tid; i < NB; i += 1024) hist[i] = 0;
    fhist[tid] = 0;
    if (tid == 0) scounter = 0;
    __syncthreads();

    // ---- pass 1: coarse histogram ----
    for (int i = tid; i < NN; i += 1024)
        atomicAdd(&hist[__float_as_uint(db[i]) >> 18], 1);
    __syncthreads();

    // ---- find coarse cutoff bucket t: smallest t with cum(t) >= PP ----
    {
        int s = 0;
#pragma unroll
        for (int u = 0; u < 8; u++) s += hist[tid * 8 + u];  // strip [8*tid, 8*tid+8)
        int sc = s;
#pragma unroll
        for (int m = 1; m < 64; m <<= 1) {
            int o = __shfl_up(sc, m);
            if (lane >= m) sc += o;
        }
        if (lane == 63) wsum[wave] = sc;
        __syncthreads();
        if (tid < 16) {
            int vc = wsum[tid];
            for (int m = 1; m < 16; m <<= 1) {
                int o = __shfl_up(vc, m);
                if (tid >= m) vc += o;
            }
            wsum[tid] = vc;
        }
        __syncthreads();
        int incl = ((wave == 0) ? 0 : wsum[wave - 1]) + sc;
        int excl = incl - s;
        if (excl < PP && incl >= PP) {  // exactly one strip crosses
            int c = excl;
#pragma unroll
            for (int u = 0; u < 8; u++) {
                int bkt = tid * 8 + u;
                int hv = hist[bkt];
                if (c < PP && c + hv >= PP) { s_t = bkt; s_below = c; }
                c += hv;
            }
        }
    }
    __syncthreads();
    int t = s_t, below = s_below;

    // ---- pass 2: fine histogram (next 10 bits) within bucket t ----
    for (int i = tid; i < NN; i += 1024) {
        unsigned bits = __float_as_uint(db[i]);
        if ((int)(bits >> 18) == t) atomicAdd(&fhist[(bits >> 8) & 1023], 1);
    }
    __syncthreads();

    // ---- find fine cutoff ft: smallest with below + finecum(ft) >= PP ----
    {
        int s = fhist[tid];
        int sc = s;
#pragma unroll
        for (int m = 1; m < 64; m <<= 1) {
            int o = __shfl_up(sc, m);
            if (lane >= m) sc += o;
        }
        if (lane == 63) wsum[wave] = sc;
        __syncthreads();
        if (tid < 16) {
            int vc = wsum[tid];
            for (int m = 1; m < 16; m <<= 1) {
                int o = __shfl_up(vc, m);
                if (tid >= m) vc += o;
            }
            wsum[tid] = vc;
        }
        __syncthreads();
        int incl = ((wave == 0) ? 0 : wsum[wave - 1]) + sc;
        int excl = incl - s;
        if (below + excl < PP && below + incl >= PP) s_ft = tid;
    }
    __syncthreads();
    int ft = s_ft;

    // ---- pass 3: collect superset of top-PP ----
    for (int i = tid; i < NN; i += 1024) {
        unsigned bits = __float_as_uint(db[i]);
        int c = (int)(bits >> 18);
        bool take = (c < t) || (c == t && (int)((bits >> 8) & 1023) <= ft);
        if (take) {
            int slot = atomicAdd(&scounter, 1);
            if (slot < CAP) { cd[slot] = db[i]; ci[slot] = i; }
        }
    }
    __syncthreads();
    int k = min(scounter, CAP);

    // ---- exact stable rank-count on k (~60) elements + weighted sum ----
    float w = 0.f, wv = 0.f;
    int a = actions[b];
    for (int s = tid; s < k; s += 1024) {
        ull key = ((ull)__float_as_uint(cd[s]) << 32) | (unsigned)ci[s];
        int cnt = 0;
        for (int j = 0; j < k; j++) {
            ull kj = ((ull)__float_as_uint(cd[j]) << 32) | (unsigned)ci[j];
            cnt += (kj < key);
        }
        if (cnt < PP) {
            float dd = fmaxf(cd[s], 0.f);
            float ww = 1.f / (dd + DELTA);
            w += ww;
            wv += ww * values[(size_t)a * NN + ci[s]];
        }
    }
#pragma unroll
    for (int m = 32; m >= 1; m >>= 1) {
        w += __shfl_xor(w, m);
        wv += __shfl_xor(wv, m);
    }
    if (lane == 0) { rw[wave] = w; rwv[wave] = wv; }
    __syncthreads();
    if (tid < 16) {
        float tw = rw[tid], twv = rwv[tid];
#pragma unroll
        for (int m = 8; m >= 1; m >>= 1) {
            tw += __shfl_xor(tw, m);
            twv += __shfl_xor(twv, m);
        }
        if (tid == 0) q[b] = twv / tw;
    }
}

extern "C" void kernel_launch(void* const* d_in, const int* in_sizes, int n_in,
                              void* d_out, int out_size, void* d_ws, size_t ws_size,
                              hipStream_t stream) {
    const float* states = (const float*)d_in[0];
    const int* actions = (const int*)d_in[1];
    const float* c1w = (const float*)d_in[2];
    const float* c1b = (const float*)d_in[3];
    const float* c2w = (const float*)d_in[4];
    const float* c2b = (const float*)d_in[5];
    const float* c3w = (const float*)d_in[6];
    const float* c3b = (const float*)d_in[7];
    const float* fcw = (const float*)d_in[8];
    const float* fcb = (const float*)d_in[9];
    const float* keys = (const float*)d_in[10];
    const float* vals = (const float*)d_in[11];
    float* out = (float*)d_out;

    float* ws = (float*)d_ws;
    float* c1o = ws;                    // 409600
    float* c2o = c1o + 409600;          // 165888
    float* c3o = c2o + 165888;          // 100352
    float* h   = c3o + 100352;          // 4096
    float* d2  = h + 4096;              // 640000
    int* cnt   = (int*)(d2 + 640000);   // 8
    int* list  = cnt + 8;               // 256

    conv1_k<<<(409600 + 255) / 256, 256, 0, stream>>>(states, c1w, c1b, c1o);
    conv2_k<<<(165888 + 255) / 256, 256, 0, stream>>>(c1o, c2w, c2b, c2o);
    conv3_k<<<(100352 + 255) / 256, 256, 0, stream>>>(c2o, c3w, c3b, c3o);
    fc_k<<<256, 256, 0, stream>>>(c3o, fcw, fcb, h);
    route_k<<<1, 64, 0, stream>>>(actions, cnt, list);
    dist3_k<<<dim3(125, AA), 256, 0, stream>>>(h, cnt, list, keys, d2);
    select_k<<<BB, 1024, 0, stream>>>(d2, vals, actions, out);
}